// Round 6
// baseline (299.676 us; speedup 1.0000x reference)
//
#include <hip/hip_runtime.h>
#include <hip/hip_bf16.h>

// RelativeGlobalAttention: B=2, S=2048, D=512, H=8, DH=64, MAX_SEQ=2048
// out0 = attention output (B,S,D); out1 = attn probs (B,H,S,S); concatenated in d_out.
//
// Identity: srel[l,k] = q[l].E[2047-l+k] for k<=l, else 0.
// logits = (QK^T + srel)/8; causal mask => masked probs exactly 0.
// No-max softmax: exp(v)/sum(exp(v)) == reference softmax up to fp32 rounding.
//
// R6 vs R5: per-tile block barriers eliminated. Rel scores extracted from qe
// MFMA output via in-register __shfl diagonal gather (Rw LDS gone). Ps
// (P transpose for PV) is wave-private LDS ordered by s_waitcnt lgkmcnt(0)
// + sched_barrier fences. Only 3 block barriers remain (lsum, O-combine).

namespace {
constexpr int kS  = 2048;
constexpr int kD  = 512;
constexpr int kH  = 8;
constexpr int kDH = 64;
constexpr int kB  = 2;

typedef __attribute__((ext_vector_type(8))) short short8;   // 8 x bf16
typedef __attribute__((ext_vector_type(4))) float f32x4;
}

#define WAVE_LDS_FENCE() do { \
    asm volatile("s_waitcnt lgkmcnt(0)" ::: "memory"); \
    __builtin_amdgcn_sched_barrier(0); \
} while (0)

__device__ __forceinline__ f32x4 mfma16(short8 a, short8 b, f32x4 c) {
    return __builtin_amdgcn_mfma_f32_16x16x32_bf16(a, b, c, 0, 0, 0);
}

__device__ __forceinline__ short bfbits(float f) {
    __hip_bfloat16 h = __float2bfloat16(f);
    return *reinterpret_cast<short*>(&h);
}

// ---------------------------------------------------------------------------
// conv: W (512x512 fp32 row-major) -> Wt (bf16 col-major [c][k]) x4; E -> bf16
// ---------------------------------------------------------------------------
__global__ __launch_bounds__(256)
void convw_kernel(const float* __restrict__ Wq, const float* __restrict__ Wk,
                  const float* __restrict__ Wv, const float* __restrict__ Wo,
                  const float* __restrict__ E,
                  ushort* __restrict__ Wqt, ushort* __restrict__ Wkt,
                  ushort* __restrict__ Wvt, ushort* __restrict__ Wot,
                  ushort* __restrict__ eb)
{
    const int z = blockIdx.z;
    const int tid = threadIdx.x;
    if (z == 4) {   // E: 2048x64 = 131072 elems
        const int idx = ((blockIdx.y * 8 + blockIdx.x) * 256 + tid) * 8;
        const float4 x = *reinterpret_cast<const float4*>(E + idx);
        const float4 y = *reinterpret_cast<const float4*>(E + idx + 4);
        short8 r;
        r[0] = bfbits(x.x); r[1] = bfbits(x.y); r[2] = bfbits(x.z); r[3] = bfbits(x.w);
        r[4] = bfbits(y.x); r[5] = bfbits(y.y); r[6] = bfbits(y.z); r[7] = bfbits(y.w);
        *reinterpret_cast<short8*>(eb + idx) = r;
        return;
    }
    const float* W = (z == 0) ? Wq : (z == 1) ? Wk : (z == 2) ? Wv : Wo;
    ushort* Wt = (z == 0) ? Wqt : (z == 1) ? Wkt : (z == 2) ? Wvt : Wot;

    __shared__ float Ws[64][65];
    const int k0 = blockIdx.x * 64;
    const int c0 = blockIdx.y * 64;
    const int cc = tid & 63;
    const int rq = tid >> 6;
    #pragma unroll
    for (int ii = 0; ii < 16; ++ii) {
        const int r = ii * 4 + rq;
        Ws[r][cc] = W[(size_t)(k0 + r) * kD + c0 + cc];
    }
    __syncthreads();
    #pragma unroll
    for (int ii = 0; ii < 16; ++ii) {
        const int r = ii * 4 + rq;
        Wt[(size_t)(c0 + r) * kD + k0 + cc] = (ushort)bfbits(Ws[cc][r]);
    }
}

// q_in/k_in/v_in fp32 (B,S,D) -> bf16
__global__ __launch_bounds__(256)
void cvta_kernel(const float* __restrict__ q, const float* __restrict__ k,
                 const float* __restrict__ v,
                 ushort* __restrict__ qb, ushort* __restrict__ kb,
                 ushort* __restrict__ vb)
{
    const int z = blockIdx.z;
    const float* src = (z == 0) ? q : (z == 1) ? k : v;
    ushort* dst = (z == 0) ? qb : (z == 1) ? kb : vb;
    const int idx = (blockIdx.x * 256 + threadIdx.x) * 8;
    const float4 x = *reinterpret_cast<const float4*>(src + idx);
    const float4 y = *reinterpret_cast<const float4*>(src + idx + 4);
    short8 r;
    r[0] = bfbits(x.x); r[1] = bfbits(x.y); r[2] = bfbits(x.z); r[3] = bfbits(x.w);
    r[4] = bfbits(y.x); r[5] = bfbits(y.y); r[6] = bfbits(y.z); r[7] = bfbits(y.w);
    *reinterpret_cast<short8*>(dst + idx) = r;
}

// ---------------------------------------------------------------------------
// MFMA GEMM core (unchanged from R5)
// ---------------------------------------------------------------------------
template<int MODE>
__device__ __forceinline__
void gemm_core(const ushort* __restrict__ A, const ushort* __restrict__ Wt,
               const float* __restrict__ bias, void* __restrict__ out)
{
    const int tid  = threadIdx.x;
    const int w    = tid >> 6;
    const int lane = tid & 63;
    const int g    = lane >> 4;
    const int n15  = lane & 15;
    const int r0   = blockIdx.x * 64 + w * 16;
    const int c0   = blockIdx.y * 32;

    f32x4 acc0 = {0.f, 0.f, 0.f, 0.f};
    f32x4 acc1 = {0.f, 0.f, 0.f, 0.f};
    const ushort* arow = A  + (size_t)(r0 + n15) * kD + g * 8;
    const ushort* b0p  = Wt + (size_t)(c0 + n15) * kD + g * 8;
    const ushort* b1p  = Wt + (size_t)(c0 + 16 + n15) * kD + g * 8;

    #pragma unroll 4
    for (int k0 = 0; k0 < kD; k0 += 32) {
        const short8 a  = *reinterpret_cast<const short8*>(arow + k0);
        const short8 b0 = *reinterpret_cast<const short8*>(b0p + k0);
        const short8 b1 = *reinterpret_cast<const short8*>(b1p + k0);
        acc0 = mfma16(a, b0, acc0);
        acc1 = mfma16(a, b1, acc1);
    }

    #pragma unroll
    for (int cg = 0; cg < 2; ++cg) {
        const f32x4 acc = cg ? acc1 : acc0;
        const int c = c0 + cg * 16 + n15;
        const float bb = bias[c];
        const int h = c >> 6, d = c & (kDH - 1);
        #pragma unroll
        for (int j = 0; j < 4; ++j) {
            const int r = r0 + g * 4 + j;
            const float val = acc[j] + bb;
            const int b = r >> 11, s2 = r & (kS - 1);
            if (MODE == 0) {
                ((float*)out)[(size_t)r * kD + c] = val;
            } else if (MODE == 1) {
                ((ushort*)out)[((size_t)(b * kH + h) * kS + s2) * kDH + d] = (ushort)bfbits(val);
            } else {
                ((ushort*)out)[((size_t)(b * kH + h) * kDH + d) * kS + s2] = (ushort)bfbits(val);
            }
        }
    }
}

__global__ __launch_bounds__(256)
void gemm_qkv_kernel(const ushort* __restrict__ qb, const ushort* __restrict__ kb,
                     const ushort* __restrict__ vb,
                     const ushort* __restrict__ Wqt, const ushort* __restrict__ Wkt,
                     const ushort* __restrict__ Wvt,
                     const float* __restrict__ bq, const float* __restrict__ bk,
                     const float* __restrict__ bv,
                     ushort* __restrict__ qh, ushort* __restrict__ kh,
                     ushort* __restrict__ vt)
{
    const int z = blockIdx.z;
    const ushort* A    = (z == 0) ? qb  : (z == 1) ? kb  : vb;
    const ushort* Wt   = (z == 0) ? Wqt : (z == 1) ? Wkt : Wvt;
    const float*  bias = (z == 0) ? bq  : (z == 1) ? bk  : bv;
    void*         out  = (z == 0) ? (void*)qh : (z == 1) ? (void*)kh : (void*)vt;
    if (z == 2) gemm_core<2>(A, Wt, bias, out);
    else        gemm_core<1>(A, Wt, bias, out);
}

__global__ __launch_bounds__(256)
void gemm_o_kernel(const ushort* __restrict__ ohb, const ushort* __restrict__ Wot,
                   const float* __restrict__ bo, float* __restrict__ out)
{
    gemm_core<0>(ohb, Wot, bo, out);
}

// ---------------------------------------------------------------------------
// Fused attention, barrier-free main loops.
// Block = (bh, 16-row strip) x 4 waves; wave w owns tiles t = w, w+4, ...
// Rel scores: qe MFMA -> in-register shfl diagonal gather:
//   R[lr][ki] = qe[lr][ki-lr+15]; same 16-lane row group, col-lane
//   (n15+15-lr)&15, register nt + ((n15+15-lr)>=16). src/cond precomputed.
// Ps (P transpose): wave-private LDS + lgkmcnt fences. Block barriers: 3.
// grid (16, 128) x 256. Default block->XCD map gives XCD = bh % 8.
// ---------------------------------------------------------------------------
__global__ __launch_bounds__(256, 4)
void attn_fused_kernel(const ushort* __restrict__ qh, const ushort* __restrict__ kh,
                       const ushort* __restrict__ vt, const ushort* __restrict__ eb,
                       float* __restrict__ attn, ushort* __restrict__ ohb)
{
    // LDS: [0,8192) Ps (4 waves x 16x64 bf16, swizzled)  -- aliased by O_s
    //      [16384,16640) lsum_s ; O_s = [0,16384) after pass B
    __shared__ __align__(16) char smem[16640];

    const int bh    = blockIdx.x;
    const int strip = 127 - (int)blockIdx.y;     // big-work-first
    const int l0    = strip * 16;
    const int tid   = threadIdx.x;
    const int w     = tid >> 6;
    const int lane  = tid & 63;
    const int g     = lane >> 4;
    const int n15   = lane & 15;
    const size_t bhS = (size_t)bh * kS;

    char*  PsB = smem + w * 2048;                // 16x64 bf16 swizzled
    float* lsum_s = (float*)(smem + 16384);

    const int T = ((l0 + 15) >> 6) + 1;          // causal 64-wide tiles

    const ushort* qrow = qh + (bhS + l0 + n15) * kDH;
    const short8 aq0 = *reinterpret_cast<const short8*>(qrow + g * 8);
    const short8 aq1 = *reinterpret_cast<const short8*>(qrow + 32 + g * 8);

    // diagonal-gather constants (per j): R[lr][ki] lives at col-lane (d&15),
    // register nt + (d>=16), d = n15 + 15 - lr, same row group.
    int  srcl[4];
    bool condj[4];
    #pragma unroll
    for (int j = 0; j < 4; ++j) {
        const int d = n15 + 15 - (g * 4 + j);
        srcl[j]  = (lane & 48) | (d & 15);
        condj[j] = (d >= 16);
    }

    // ---------------- pass A: row sums (no barriers) ----------------
    float lsum[4] = {0.f, 0.f, 0.f, 0.f};
    for (int t = w; t < T; t += 4) {
        const int k0 = t * 64;
        float sl[4][4];
        #pragma unroll
        for (int nt = 0; nt < 4; ++nt) {
            const ushort* krow = kh + (bhS + k0 + nt * 16 + n15) * kDH;
            f32x4 acc = {0.f, 0.f, 0.f, 0.f};
            acc = mfma16(aq0, *reinterpret_cast<const short8*>(krow + g * 8), acc);
            acc = mfma16(aq1, *reinterpret_cast<const short8*>(krow + 32 + g * 8), acc);
            #pragma unroll
            for (int j = 0; j < 4; ++j) sl[nt][j] = acc[j];
        }
        const int m_lo = 2032 + k0 - l0;
        f32x4 qe[5];
        #pragma unroll
        for (int nt = 0; nt < 5; ++nt) {
            int er = m_lo + nt * 16 + n15;
            if (er > kS - 1) er = kS - 1;        // clamped rows only feed masked elems
            const ushort* erow = eb + (size_t)er * kDH;
            f32x4 acc = {0.f, 0.f, 0.f, 0.f};
            acc = mfma16(aq0, *reinterpret_cast<const short8*>(erow + g * 8), acc);
            qe[nt] = mfma16(aq1, *reinterpret_cast<const short8*>(erow + 32 + g * 8), acc);
        }
        #pragma unroll
        for (int j = 0; j < 4; ++j) {
            float sh[5];
            #pragma unroll
            for (int q5 = 0; q5 < 5; ++q5) sh[q5] = __shfl(qe[q5][j], srcl[j]);
            const int lr = g * 4 + j;
            #pragma unroll
            for (int nt = 0; nt < 4; ++nt) {
                const float rel = condj[j] ? sh[nt + 1] : sh[nt];
                const int ki = nt * 16 + n15;
                float v = (sl[nt][j] + rel) * 0.125f;
                v = fminf(v, 60.f);
                lsum[j] += (k0 + ki <= l0 + lr) ? __expf(v) : 0.f;
            }
        }
    }
    #pragma unroll
    for (int j = 0; j < 4; ++j) {
        float s = lsum[j];
        #pragma unroll
        for (int off = 1; off < 16; off <<= 1) s += __shfl_xor(s, off);
        if (n15 == 0) lsum_s[w * 16 + g * 4 + j] = s;
    }
    __syncthreads();                             // [barrier 1] lsum exchange

    float linv[4];
    #pragma unroll
    for (int j = 0; j < 4; ++j) {
        const int r = g * 4 + j;
        linv[j] = 1.f / (lsum_s[r] + lsum_s[16 + r] + lsum_s[32 + r] + lsum_s[48 + r]);
    }

    // ---------------- pass B: emit + PV (wave-local fences only) ----------------
    f32x4 o[4];
    #pragma unroll
    for (int nt = 0; nt < 4; ++nt) o[nt] = (f32x4){0.f, 0.f, 0.f, 0.f};
    const int swr = (n15 & 7) << 4;

    for (int t = w; t < 32; t += 4) {
        const int k0 = t * 64;
        if (t >= T) {                            // fully masked: stream zeros
            const float4 z = make_float4(0.f, 0.f, 0.f, 0.f);
            #pragma unroll
            for (int rr = 0; rr < 4; ++rr) {
                const int row = rr * 4 + g;
                *reinterpret_cast<float4*>(attn + (bhS + l0 + row) * kS + k0 + n15 * 4) = z;
            }
            continue;
        }
        float sl[4][4];
        #pragma unroll
        for (int nt = 0; nt < 4; ++nt) {
            const ushort* krow = kh + (bhS + k0 + nt * 16 + n15) * kDH;
            f32x4 acc = {0.f, 0.f, 0.f, 0.f};
            acc = mfma16(aq0, *reinterpret_cast<const short8*>(krow + g * 8), acc);
            acc = mfma16(aq1, *reinterpret_cast<const short8*>(krow + 32 + g * 8), acc);
            #pragma unroll
            for (int j = 0; j < 4; ++j) sl[nt][j] = acc[j];
        }
        const int m_lo = 2032 + k0 - l0;
        f32x4 qe[5];
        #pragma unroll
        for (int nt = 0; nt < 5; ++nt) {
            int er = m_lo + nt * 16 + n15;
            if (er > kS - 1) er = kS - 1;
            const ushort* erow = eb + (size_t)er * kDH;
            f32x4 acc = {0.f, 0.f, 0.f, 0.f};
            acc = mfma16(aq0, *reinterpret_cast<const short8*>(erow + g * 8), acc);
            qe[nt] = mfma16(aq1, *reinterpret_cast<const short8*>(erow + 32 + g * 8), acc);
        }
        #pragma unroll
        for (int j = 0; j < 4; ++j) {
            float sh[5];
            #pragma unroll
            for (int q5 = 0; q5 < 5; ++q5) sh[q5] = __shfl(qe[q5][j], srcl[j]);
            const int lr = g * 4 + j;
            const int swl = (lr & 7) << 4;
            #pragma unroll
            for (int nt = 0; nt < 4; ++nt) {
                const float rel = condj[j] ? sh[nt + 1] : sh[nt];
                const int ki = nt * 16 + n15;
                float v = (sl[nt][j] + rel) * 0.125f;
                v = fminf(v, 60.f);
                const float pe = (k0 + ki <= l0 + lr) ? __expf(v) * linv[j] : 0.f;
                attn[(bhS + l0 + lr) * kS + k0 + ki] = pe;
                const int byte = lr * 128 + ((((ki >> 3) << 4) ^ swl) | ((ki & 7) * 2));
                *(__hip_bfloat16*)(PsB + byte) = __float2bfloat16(pe);
            }
        }
        WAVE_LDS_FENCE();                        // Ps writes -> reads
        const short8 pa0 = *reinterpret_cast<const short8*>(PsB + n15 * 128 + (((0 + g) << 4) ^ swr));
        const short8 pa1 = *reinterpret_cast<const short8*>(PsB + n15 * 128 + (((4 + g) << 4) ^ swr));
        WAVE_LDS_FENCE();                        // Ps reads retired (WAR vs next tile)
        #pragma unroll
        for (int nt = 0; nt < 4; ++nt) {
            const ushort* vrow = vt + ((size_t)bh * kDH + nt * 16 + n15) * kS + k0;
            o[nt] = mfma16(pa0, *reinterpret_cast<const short8*>(vrow + g * 8), o[nt]);
            o[nt] = mfma16(pa1, *reinterpret_cast<const short8*>(vrow + 32 + g * 8), o[nt]);
        }
    }

    // ---------------- O combine (O_s aliases Ps region) ----------------
    __syncthreads();                             // [barrier 2] all Ps reads done
    float* O_s = (float*)smem;                   // 4 waves x 16x64 f32 = 16 KiB
    #pragma unroll
    for (int nt = 0; nt < 4; ++nt)
        #pragma unroll
        for (int j = 0; j < 4; ++j)
            O_s[w * 1024 + (g * 4 + j) * 64 + nt * 16 + n15] = o[nt][j];
    __syncthreads();                             // [barrier 3]

    const int b = bh >> 3, h = bh & 7;
    #pragma unroll
    for (int i = tid; i < 1024; i += 256) {
        const int r = i >> 6, c = i & 63;
        const float acc = O_s[i] + O_s[1024 + i] + O_s[2048 + i] + O_s[3072 + i];
        ohb[((size_t)b * kS + l0 + r) * kD + h * kDH + c] = (ushort)bfbits(acc);
    }
}

// ---------------------------------------------------------------------------
extern "C" void kernel_launch(void* const* d_in, const int* in_sizes, int n_in,
                              void* d_out, int out_size, void* d_ws, size_t ws_size,
                              hipStream_t stream)
{
    const float* q_in = (const float*)d_in[0];
    const float* k_in = (const float*)d_in[1];
    const float* v_in = (const float*)d_in[2];
    const float* Wq = (const float*)d_in[4];
    const float* bq = (const float*)d_in[5];
    const float* Wk = (const float*)d_in[6];
    const float* bk = (const float*)d_in[7];
    const float* Wv = (const float*)d_in[8];
    const float* bv = (const float*)d_in[9];
    const float* Wo = (const float*)d_in[10];
    const float* bo = (const float*)d_in[11];
    const float* E  = (const float*)d_in[12];

    float* out  = (float*)d_out;                          // (B,S,D)
    float* attn = (float*)d_out + (size_t)kB * kS * kD;   // (B,H,S,S)

    // workspace: all bf16 (~31.7 MB)
    ushort* qh  = (ushort*)d_ws;          // (B,H,S,DH)
    ushort* kh  = qh  + 2097152;          // (B,H,S,DH)
    ushort* vt  = kh  + 2097152;          // (B,H,DH,S)
    ushort* ohb = vt  + 2097152;          // (B,S,D)
    ushort* qb  = ohb + 2097152;          // (B,S,D) inputs in bf16
    ushort* kb  = qb  + 2097152;
    ushort* vb  = kb  + 2097152;
    ushort* eb  = vb  + 2097152;          // (2048,64)
    ushort* Wqt = eb  + 131072;           // col-major 512x512
    ushort* Wkt = Wqt + 262144;
    ushort* Wvt = Wkt + 262144;
    ushort* Wot = Wvt + 262144;

    convw_kernel<<<dim3(8, 8, 5), 256, 0, stream>>>(Wq, Wk, Wv, Wo, E,
                                                    Wqt, Wkt, Wvt, Wot, eb);
    cvta_kernel<<<dim3(1024, 1, 3), 256, 0, stream>>>(q_in, k_in, v_in, qb, kb, vb);
    gemm_qkv_kernel<<<dim3(64, 16, 3), 256, 0, stream>>>(qb, kb, vb,
                                                         Wqt, Wkt, Wvt,
                                                         bq, bk, bv, qh, kh, vt);
    attn_fused_kernel<<<dim3(16, 128), 256, 0, stream>>>(qh, kh, vt, eb, attn, ohb);
    gemm_o_kernel<<<dim3(64, 16), 256, 0, stream>>>(ohb, Wot, bo, out);
}